// Round 3
// baseline (147.591 us; speedup 1.0000x reference)
//
#include <hip/hip_runtime.h>
#include <hip/hip_bf16.h>

typedef __attribute__((ext_vector_type(8))) short short8;
typedef __attribute__((ext_vector_type(4))) float f32x4;

#define NQ 32      // queries
#define NM 32      // query tokens
#define NH 128     // head dim
#define ND 512     // docs
#define NN 180     // doc tokens
#define NNP 192    // padded doc tokens (12 tiles of 16)
#define LSTR 136   // LDS row stride in shorts (272 B = 17 x 16B slots -> uniform bank spread)

static __device__ __forceinline__ unsigned short f2bf(float x) {
  __hip_bfloat16 h = __float2bfloat16(x);
  return __builtin_bit_cast(unsigned short, h);
}

// Qb = bf16(Q * q_mask), [32*32][128]
__global__ __launch_bounds__(256, 1) void prep_q_kernel(
    const float* __restrict__ Q, const int* __restrict__ qmask,
    unsigned short* __restrict__ Qb) {
  int idx = blockIdx.x * 256 + threadIdx.x;   // float4 index, 32768 total
  int row = idx >> 5;                          // qm row (32 float4 per row)
  float m = (float)qmask[row];
  float4 v = reinterpret_cast<const float4*>(Q)[idx];
  unsigned int lo = (unsigned)f2bf(v.x * m) | ((unsigned)f2bf(v.y * m) << 16);
  unsigned int hi = (unsigned)f2bf(v.z * m) | ((unsigned)f2bf(v.w * m) << 16);
  reinterpret_cast<uint2*>(Qb)[idx] = make_uint2(lo, hi);
}

static __device__ __forceinline__ f32x4 max4(f32x4 a, f32x4 b) {
  f32x4 r;
  r[0] = fmaxf(a[0], b[0]); r[1] = fmaxf(a[1], b[1]);
  r[2] = fmaxf(a[2], b[2]); r[3] = fmaxf(a[3], b[3]);
  return r;
}

// one workgroup per doc d; 4 waves; wave w owns queries w*8..w*8+7 (processed in
// pairs sharing each D-fragment ds_read). Operands swapped: C[n,m] = mfma(Dfrag, Qfrag)
// so max-over-n = per-lane j-fold + xor16/xor32. No cross-wave reduction, no LDS alias.
__global__ __launch_bounds__(256, 2) void maxsim_kernel(
    const float* __restrict__ D, const int* __restrict__ dmask,
    const unsigned short* __restrict__ Qb, float* __restrict__ out) {
  __shared__ unsigned short Dlds[NNP * LSTR];  // 52224 B
  const int d = blockIdx.x;
  const int tid = threadIdx.x;
  const int lane = tid & 63;
  const int w = tid >> 6;
  const float NEG = -__builtin_inff();

  // ---- stage masked D -> LDS bf16 ----
  const float4* Dsrc = reinterpret_cast<const float4*>(D) + d * (NN * NH / 4);
  for (int i = tid; i < NN * (NH / 4); i += 256) {
    int row = i >> 5;
    int c4 = i & 31;
    float m = (float)dmask[d * NN + row];
    float4 v = Dsrc[i];
    unsigned int lo = (unsigned)f2bf(v.x * m) | ((unsigned)f2bf(v.y * m) << 16);
    unsigned int hi = (unsigned)f2bf(v.z * m) | ((unsigned)f2bf(v.w * m) << 16);
    *reinterpret_cast<uint2*>(&Dlds[row * LSTR + c4 * 4]) = make_uint2(lo, hi);
  }
  for (int i = tid; i < (NNP - NN) * (NH / 4); i += 256) {  // zero pad rows 180..191
    int row = NN + (i >> 5);
    int c4 = i & 31;
    *reinterpret_cast<uint2*>(&Dlds[row * LSTR + c4 * 4]) = make_uint2(0u, 0u);
  }
  __syncthreads();

  const int bl = lane & 15;   // fragment row(n)/col(m) within tile
  const int bg = lane >> 4;   // k-group

  float rm[8][2];             // deferred per-q per-mt partial maxes (scalar per lane)

  #pragma unroll
  for (int p = 0; p < 4; ++p) {
    const int q0 = w * 8 + p * 2;
    const unsigned short* Qp0 = Qb + (q0 + 0) * (NM * NH);
    const unsigned short* Qp1 = Qb + (q0 + 1) * (NM * NH);

    // B operand fragments for the two queries of this pair
    short8 Qf[2][2][4];  // [qi][mt][ks]
    #pragma unroll
    for (int mt = 0; mt < 2; ++mt) {
      #pragma unroll
      for (int ks = 0; ks < 4; ++ks) {
        Qf[0][mt][ks] = *reinterpret_cast<const short8*>(
            Qp0 + (mt * 16 + bl) * NH + ks * 32 + bg * 8);
        Qf[1][mt][ks] = *reinterpret_cast<const short8*>(
            Qp1 + (mt * 16 + bl) * NH + ks * 32 + bg * 8);
      }
    }

    f32x4 run00 = {NEG, NEG, NEG, NEG};
    f32x4 run01 = run00, run10 = run00, run11 = run00;

    #pragma unroll
    for (int nt = 0; nt < 12; ++nt) {
      // A operand (D rows) for this n-tile, shared by both queries
      short8 Da[4];
      #pragma unroll
      for (int ks = 0; ks < 4; ++ks)
        Da[ks] = *reinterpret_cast<const short8*>(
            &Dlds[(nt * 16 + bl) * LSTR + ks * 32 + bg * 8]);

      f32x4 a00 = {0.f, 0.f, 0.f, 0.f};
      f32x4 a01 = a00, a10 = a00, a11 = a00;
      #pragma unroll
      for (int ks = 0; ks < 4; ++ks) {
        a00 = __builtin_amdgcn_mfma_f32_16x16x32_bf16(Da[ks], Qf[0][0][ks], a00, 0, 0, 0);
        a01 = __builtin_amdgcn_mfma_f32_16x16x32_bf16(Da[ks], Qf[0][1][ks], a01, 0, 0, 0);
        a10 = __builtin_amdgcn_mfma_f32_16x16x32_bf16(Da[ks], Qf[1][0][ks], a10, 0, 0, 0);
        a11 = __builtin_amdgcn_mfma_f32_16x16x32_bf16(Da[ks], Qf[1][1][ks], a11, 0, 0, 0);
      }

      if (nt == 11) {
        // tile 11 rows are n=176..191; only n<180 (bg==0) are real doc tokens
        #pragma unroll
        for (int j = 0; j < 4; ++j) {
          a00[j] = (bg == 0) ? a00[j] : NEG;
          a01[j] = (bg == 0) ? a01[j] : NEG;
          a10[j] = (bg == 0) ? a10[j] : NEG;
          a11[j] = (bg == 0) ? a11[j] : NEG;
        }
      }
      run00 = max4(run00, a00);
      run01 = max4(run01, a01);
      run10 = max4(run10, a10);
      run11 = max4(run11, a11);
    }

    // fold j (4 n-rows per lane) -> one scalar per (qi, mt)
    rm[p * 2 + 0][0] = fmaxf(fmaxf(run00[0], run00[1]), fmaxf(run00[2], run00[3]));
    rm[p * 2 + 0][1] = fmaxf(fmaxf(run01[0], run01[1]), fmaxf(run01[2], run01[3]));
    rm[p * 2 + 1][0] = fmaxf(fmaxf(run10[0], run10[1]), fmaxf(run10[2], run10[3]));
    rm[p * 2 + 1][1] = fmaxf(fmaxf(run11[0], run11[1]), fmaxf(run11[2], run11[3]));
  }

  // ---- deferred tails: 8 independent shuffle chains, fully pipelined ----
  #pragma unroll
  for (int qi = 0; qi < 8; ++qi) {
    float a = rm[qi][0];
    float b = rm[qi][1];
    a = fmaxf(a, __shfl_xor(a, 16));  // combine k-groups (n-row quarters)
    a = fmaxf(a, __shfl_xor(a, 32));
    b = fmaxf(b, __shfl_xor(b, 16));
    b = fmaxf(b, __shfl_xor(b, 32));
    float s = a + b;                  // m = bl and m = bl+16
    s += __shfl_xor(s, 1);
    s += __shfl_xor(s, 2);
    s += __shfl_xor(s, 4);
    s += __shfl_xor(s, 8);            // sum over the 16 bl classes
    if (lane == 0) out[(w * 8 + qi) * ND + d] = s;
  }
}

extern "C" void kernel_launch(void* const* d_in, const int* in_sizes, int n_in,
                              void* d_out, int out_size, void* d_ws, size_t ws_size,
                              hipStream_t stream) {
  const float* Q = (const float*)d_in[0];
  const float* D = (const float*)d_in[1];
  const int* qmask = (const int*)d_in[2];
  const int* dmask = (const int*)d_in[3];
  float* out = (float*)d_out;
  unsigned short* Qb = (unsigned short*)d_ws;  // 32*32*128 bf16 = 256 KB

  prep_q_kernel<<<(NQ * NM * NH / 4) / 256, 256, 0, stream>>>(Q, qmask, Qb);
  maxsim_kernel<<<ND, 256, 0, stream>>>(D, dmask, Qb, out);
}

// Round 4
// 95.836 us; speedup vs baseline: 1.5400x; 1.5400x over previous
//
#include <hip/hip_runtime.h>
#include <hip/hip_bf16.h>

typedef __attribute__((ext_vector_type(8))) short short8;
typedef __attribute__((ext_vector_type(4))) float f32x4;

#define NQ 32      // queries
#define NM 32      // query tokens
#define NH 128     // head dim
#define ND 512     // docs
#define NN 180     // doc tokens
#define NNP 192    // padded doc tokens (12 tiles of 16)
#define LSTR 136   // LDS row stride in shorts (272 B = 17 x 16B slots -> uniform bank spread)

static __device__ __forceinline__ unsigned short f2bf(float x) {
  __hip_bfloat16 h = __float2bfloat16(x);
  return __builtin_bit_cast(unsigned short, h);
}

// Qb = bf16(Q * q_mask), [32*32][128]
__global__ __launch_bounds__(256, 1) void prep_q_kernel(
    const float* __restrict__ Q, const int* __restrict__ qmask,
    unsigned short* __restrict__ Qb) {
  int idx = blockIdx.x * 256 + threadIdx.x;   // float4 index, 32768 total
  int row = idx >> 5;                          // qm row (32 float4 per row)
  float m = (float)qmask[row];
  float4 v = reinterpret_cast<const float4*>(Q)[idx];
  unsigned int lo = (unsigned)f2bf(v.x * m) | ((unsigned)f2bf(v.y * m) << 16);
  unsigned int hi = (unsigned)f2bf(v.z * m) | ((unsigned)f2bf(v.w * m) << 16);
  reinterpret_cast<uint2*>(Qb)[idx] = make_uint2(lo, hi);
}

static __device__ __forceinline__ f32x4 max4(f32x4 a, f32x4 b) {
  f32x4 r;
  r[0] = fmaxf(a[0], b[0]); r[1] = fmaxf(a[1], b[1]);
  r[2] = fmaxf(a[2], b[2]); r[3] = fmaxf(a[3], b[3]);
  return r;
}

// one workgroup per doc d; 4 waves; wave w owns queries w*8..w*8+7, processed in
// pairs sharing each D-fragment ds_read; 2-n-tile blocking -> 8 independent MFMA
// chains (2nt x 2qi x 2mt) per inner iter. Operands swapped: C[n,m]=mfma(Dfrag,Qfrag)
// so max-over-n is a per-lane fold + xor16/xor32. NO VGPR cap: grid (512 blocks)
// limits us to 2 waves/SIMD anyway, so up to 256 VGPR is occupancy-free.
__global__ __launch_bounds__(256) void maxsim_kernel(
    const float* __restrict__ D, const int* __restrict__ dmask,
    const unsigned short* __restrict__ Qb, float* __restrict__ out) {
  __shared__ unsigned short Dlds[NNP * LSTR];  // 52224 B
  const int d = blockIdx.x;
  const int tid = threadIdx.x;
  const int lane = tid & 63;
  const int w = tid >> 6;
  const float NEG = -__builtin_inff();

  // ---- stage masked D -> LDS bf16 ----
  const float4* Dsrc = reinterpret_cast<const float4*>(D) + d * (NN * NH / 4);
  for (int i = tid; i < NN * (NH / 4); i += 256) {
    int row = i >> 5;
    int c4 = i & 31;
    float m = (float)dmask[d * NN + row];
    float4 v = Dsrc[i];
    unsigned int lo = (unsigned)f2bf(v.x * m) | ((unsigned)f2bf(v.y * m) << 16);
    unsigned int hi = (unsigned)f2bf(v.z * m) | ((unsigned)f2bf(v.w * m) << 16);
    *reinterpret_cast<uint2*>(&Dlds[row * LSTR + c4 * 4]) = make_uint2(lo, hi);
  }
  for (int i = tid; i < (NNP - NN) * (NH / 4); i += 256) {  // zero pad rows 180..191
    int row = NN + (i >> 5);
    int c4 = i & 31;
    *reinterpret_cast<uint2*>(&Dlds[row * LSTR + c4 * 4]) = make_uint2(0u, 0u);
  }
  __syncthreads();

  const int bl = lane & 15;   // fragment row(n)/col(m) within tile
  const int bg = lane >> 4;   // k-group

  float rm[8][2];             // deferred per-q per-mt partial maxes (scalar per lane)

  #pragma unroll
  for (int p = 0; p < 4; ++p) {
    const int q0 = w * 8 + p * 2;
    const unsigned short* Qp0 = Qb + (q0 + 0) * (NM * NH);
    const unsigned short* Qp1 = Qb + (q0 + 1) * (NM * NH);

    // B operand fragments for the two queries of this pair (64 VGPR)
    short8 Qf[2][2][4];  // [qi][mt][ks]
    #pragma unroll
    for (int mt = 0; mt < 2; ++mt) {
      #pragma unroll
      for (int ks = 0; ks < 4; ++ks) {
        Qf[0][mt][ks] = *reinterpret_cast<const short8*>(
            Qp0 + (mt * 16 + bl) * NH + ks * 32 + bg * 8);
        Qf[1][mt][ks] = *reinterpret_cast<const short8*>(
            Qp1 + (mt * 16 + bl) * NH + ks * 32 + bg * 8);
      }
    }

    f32x4 run[2][2];  // [qi][mt]
    #pragma unroll
    for (int qi = 0; qi < 2; ++qi)
      #pragma unroll
      for (int mt = 0; mt < 2; ++mt)
        run[qi][mt] = (f32x4){NEG, NEG, NEG, NEG};

    #pragma unroll
    for (int ntp = 0; ntp < 6; ++ntp) {   // 2 n-tiles per iter
      short8 Da[2][4];
      #pragma unroll
      for (int nti = 0; nti < 2; ++nti)
        #pragma unroll
        for (int ks = 0; ks < 4; ++ks)
          Da[nti][ks] = *reinterpret_cast<const short8*>(
              &Dlds[((ntp * 2 + nti) * 16 + bl) * LSTR + ks * 32 + bg * 8]);

      // 8 independent accumulator chains
      f32x4 acc[2][2][2];  // [nti][qi][mt]
      #pragma unroll
      for (int nti = 0; nti < 2; ++nti)
        #pragma unroll
        for (int qi = 0; qi < 2; ++qi)
          #pragma unroll
          for (int mt = 0; mt < 2; ++mt)
            acc[nti][qi][mt] = (f32x4){0.f, 0.f, 0.f, 0.f};

      #pragma unroll
      for (int ks = 0; ks < 4; ++ks)
        #pragma unroll
        for (int nti = 0; nti < 2; ++nti)
          #pragma unroll
          for (int qi = 0; qi < 2; ++qi)
            #pragma unroll
            for (int mt = 0; mt < 2; ++mt)
              acc[nti][qi][mt] = __builtin_amdgcn_mfma_f32_16x16x32_bf16(
                  Da[nti][ks], Qf[qi][mt][ks], acc[nti][qi][mt], 0, 0, 0);

      // fold into running max; tile 11 (ntp==5, nti==1): only bg==0 rows (n=176..179) real
      #pragma unroll
      for (int nti = 0; nti < 2; ++nti) {
        const bool isTail = (ntp == 5) && (nti == 1);
        #pragma unroll
        for (int qi = 0; qi < 2; ++qi)
          #pragma unroll
          for (int mt = 0; mt < 2; ++mt) {
            f32x4 v = acc[nti][qi][mt];
            if (isTail) {
              #pragma unroll
              for (int j = 0; j < 4; ++j) v[j] = (bg == 0) ? v[j] : NEG;
            }
            run[qi][mt] = max4(run[qi][mt], v);
          }
      }
    }

    // fold j (4 n-rows per lane) -> one scalar per (qi, mt)
    #pragma unroll
    for (int qi = 0; qi < 2; ++qi)
      #pragma unroll
      for (int mt = 0; mt < 2; ++mt)
        rm[p * 2 + qi][mt] = fmaxf(fmaxf(run[qi][mt][0], run[qi][mt][1]),
                                   fmaxf(run[qi][mt][2], run[qi][mt][3]));
  }

  // ---- deferred tails: 8 independent shuffle chains, fully pipelined ----
  #pragma unroll
  for (int qi = 0; qi < 8; ++qi) {
    float a = rm[qi][0];
    float b = rm[qi][1];
    a = fmaxf(a, __shfl_xor(a, 16));  // combine k-groups (n-row quarters)
    a = fmaxf(a, __shfl_xor(a, 32));
    b = fmaxf(b, __shfl_xor(b, 16));
    b = fmaxf(b, __shfl_xor(b, 32));
    float s = a + b;                  // m = bl and m = bl+16
    s += __shfl_xor(s, 1);
    s += __shfl_xor(s, 2);
    s += __shfl_xor(s, 4);
    s += __shfl_xor(s, 8);            // sum over the 16 bl classes
    if (lane == 0) out[(w * 8 + qi) * ND + d] = s;
  }
}

extern "C" void kernel_launch(void* const* d_in, const int* in_sizes, int n_in,
                              void* d_out, int out_size, void* d_ws, size_t ws_size,
                              hipStream_t stream) {
  const float* Q = (const float*)d_in[0];
  const float* D = (const float*)d_in[1];
  const int* qmask = (const int*)d_in[2];
  const int* dmask = (const int*)d_in[3];
  float* out = (float*)d_out;
  unsigned short* Qb = (unsigned short*)d_ws;  // 32*32*128 bf16 = 256 KB

  prep_q_kernel<<<(NQ * NM * NH / 4) / 256, 256, 0, stream>>>(Q, qmask, Qb);
  maxsim_kernel<<<ND, 256, 0, stream>>>(D, dmask, Qb, out);
}

// Round 5
// 88.647 us; speedup vs baseline: 1.6649x; 1.0811x over previous
//
#include <hip/hip_runtime.h>
#include <hip/hip_bf16.h>

typedef __attribute__((ext_vector_type(8))) short short8;
typedef __attribute__((ext_vector_type(4))) float f32x4;

#define NQ 32      // queries
#define NM 32      // query tokens
#define NH 128     // head dim
#define ND 512     // docs
#define NN 180     // doc tokens
#define NNP 192    // padded doc tokens (12 tiles of 16)
#define LSTR 136   // LDS row stride in shorts (272 B)

static __device__ __forceinline__ unsigned short f2bf(float x) {
  __hip_bfloat16 h = __float2bfloat16(x);
  return __builtin_bit_cast(unsigned short, h);
}

// Qb = bf16(Q * q_mask), [32*32][128]
__global__ __launch_bounds__(256, 1) void prep_q_kernel(
    const float* __restrict__ Q, const int* __restrict__ qmask,
    unsigned short* __restrict__ Qb) {
  int idx = blockIdx.x * 256 + threadIdx.x;   // float4 index, 32768 total
  int row = idx >> 5;                          // qm row (32 float4 per row)
  float m = (float)qmask[row];
  float4 v = reinterpret_cast<const float4*>(Q)[idx];
  unsigned int lo = (unsigned)f2bf(v.x * m) | ((unsigned)f2bf(v.y * m) << 16);
  unsigned int hi = (unsigned)f2bf(v.z * m) | ((unsigned)f2bf(v.w * m) << 16);
  reinterpret_cast<uint2*>(Qb)[idx] = make_uint2(lo, hi);
}

static __device__ __forceinline__ f32x4 max4(f32x4 a, f32x4 b) {
  f32x4 r;
  r[0] = fmaxf(a[0], b[0]); r[1] = fmaxf(a[1], b[1]);
  r[2] = fmaxf(a[2], b[2]); r[3] = fmaxf(a[3], b[3]);
  return r;
}

// one workgroup per doc d; 4 waves; wave w owns queries w*8..w*8+7, processed in
// pairs. The pair loop is a RUNTIME loop (#pragma unroll 1): only one pair's
// working set (Qf 64 + Da 32 + acc 32 + run 16 ~ 180 VGPR) is ever live -> no
// spill (R3/R4 lesson: unrolling it overlapped 4 pairs' live ranges -> scratch).
// Operands swapped: C[n,m] = mfma(Dfrag, Qfrag); max-over-n = j-fold + xor16/32.
// Reduction tail done inside the loop (no runtime-indexed rm[] array).
__global__ __launch_bounds__(256, 2) void maxsim_kernel(
    const float* __restrict__ D, const int* __restrict__ dmask,
    const unsigned short* __restrict__ Qb, float* __restrict__ out) {
  __shared__ unsigned short Dlds[NNP * LSTR];  // 52224 B
  const int d = blockIdx.x;
  const int tid = threadIdx.x;
  const int lane = tid & 63;
  const int w = tid >> 6;
  const float NEG = -__builtin_inff();

  // ---- stage masked D -> LDS bf16 ----
  const float4* Dsrc = reinterpret_cast<const float4*>(D) + d * (NN * NH / 4);
  for (int i = tid; i < NN * (NH / 4); i += 256) {
    int row = i >> 5;
    int c4 = i & 31;
    float m = (float)dmask[d * NN + row];
    float4 v = Dsrc[i];
    unsigned int lo = (unsigned)f2bf(v.x * m) | ((unsigned)f2bf(v.y * m) << 16);
    unsigned int hi = (unsigned)f2bf(v.z * m) | ((unsigned)f2bf(v.w * m) << 16);
    *reinterpret_cast<uint2*>(&Dlds[row * LSTR + c4 * 4]) = make_uint2(lo, hi);
  }
  for (int i = tid; i < (NNP - NN) * (NH / 4); i += 256) {  // zero pad rows 180..191
    int row = NN + (i >> 5);
    int c4 = i & 31;
    *reinterpret_cast<uint2*>(&Dlds[row * LSTR + c4 * 4]) = make_uint2(0u, 0u);
  }
  __syncthreads();

  const int bl = lane & 15;   // fragment row(n)/col(m) within tile
  const int bg = lane >> 4;   // k-group / n-quarter

  #pragma unroll 1
  for (int p = 0; p < 4; ++p) {
    const int q0 = w * 8 + p * 2;
    const unsigned short* Qp0 = Qb + (q0 + 0) * (NM * NH);
    const unsigned short* Qp1 = Qb + (q0 + 1) * (NM * NH);

    // B operand fragments for the two queries of this pair (64 VGPR)
    short8 Qf[2][2][4];  // [qi][mt][ks]
    #pragma unroll
    for (int mt = 0; mt < 2; ++mt) {
      #pragma unroll
      for (int ks = 0; ks < 4; ++ks) {
        Qf[0][mt][ks] = *reinterpret_cast<const short8*>(
            Qp0 + (mt * 16 + bl) * NH + ks * 32 + bg * 8);
        Qf[1][mt][ks] = *reinterpret_cast<const short8*>(
            Qp1 + (mt * 16 + bl) * NH + ks * 32 + bg * 8);
      }
    }

    f32x4 run[2][2];  // [qi][mt]
    #pragma unroll
    for (int qi = 0; qi < 2; ++qi)
      #pragma unroll
      for (int mt = 0; mt < 2; ++mt)
        run[qi][mt] = (f32x4){NEG, NEG, NEG, NEG};

    #pragma unroll
    for (int ntp = 0; ntp < 6; ++ntp) {   // 2 n-tiles per iter, Da shared by the pair
      short8 Da[2][4];
      #pragma unroll
      for (int nti = 0; nti < 2; ++nti)
        #pragma unroll
        for (int ks = 0; ks < 4; ++ks)
          Da[nti][ks] = *reinterpret_cast<const short8*>(
              &Dlds[((ntp * 2 + nti) * 16 + bl) * LSTR + ks * 32 + bg * 8]);

      // 8 independent accumulator chains
      f32x4 acc[2][2][2];  // [nti][qi][mt]
      #pragma unroll
      for (int nti = 0; nti < 2; ++nti)
        #pragma unroll
        for (int qi = 0; qi < 2; ++qi)
          #pragma unroll
          for (int mt = 0; mt < 2; ++mt)
            acc[nti][qi][mt] = (f32x4){0.f, 0.f, 0.f, 0.f};

      #pragma unroll
      for (int ks = 0; ks < 4; ++ks)
        #pragma unroll
        for (int nti = 0; nti < 2; ++nti)
          #pragma unroll
          for (int qi = 0; qi < 2; ++qi)
            #pragma unroll
            for (int mt = 0; mt < 2; ++mt)
              acc[nti][qi][mt] = __builtin_amdgcn_mfma_f32_16x16x32_bf16(
                  Da[nti][ks], Qf[qi][mt][ks], acc[nti][qi][mt], 0, 0, 0);

      // fold into running max; tile 11 (ntp==5, nti==1): rows n=176+bg*4+j, only bg==0 real
      #pragma unroll
      for (int nti = 0; nti < 2; ++nti) {
        const bool isTail = (ntp == 5) && (nti == 1);
        #pragma unroll
        for (int qi = 0; qi < 2; ++qi)
          #pragma unroll
          for (int mt = 0; mt < 2; ++mt) {
            f32x4 v = acc[nti][qi][mt];
            if (isTail) {
              #pragma unroll
              for (int j = 0; j < 4; ++j) v[j] = (bg == 0) ? v[j] : NEG;
            }
            run[qi][mt] = max4(run[qi][mt], v);
          }
      }
    }

    // ---- in-loop reduction tail (~10 shuffles per q) ----
    #pragma unroll
    for (int qi = 0; qi < 2; ++qi) {
      // j-fold: per-lane max over its 4 n-rows
      float a = fmaxf(fmaxf(run[qi][0][0], run[qi][0][1]),
                      fmaxf(run[qi][0][2], run[qi][0][3]));   // mt=0 (m = bl)
      float b = fmaxf(fmaxf(run[qi][1][0], run[qi][1][1]),
                      fmaxf(run[qi][1][2], run[qi][1][3]));   // mt=1 (m = bl+16)
      // combine the 4 n-quarters (bg groups)
      a = fmaxf(a, __shfl_xor(a, 16));
      a = fmaxf(a, __shfl_xor(a, 32));
      b = fmaxf(b, __shfl_xor(b, 16));
      b = fmaxf(b, __shfl_xor(b, 32));
      float s = a + b;                  // m = bl and m = bl+16
      s += __shfl_xor(s, 1);            // sum over the 16 bl classes
      s += __shfl_xor(s, 2);
      s += __shfl_xor(s, 4);
      s += __shfl_xor(s, 8);
      if (lane == 0) out[(q0 + qi) * ND + d] = s;
    }
  }
}

extern "C" void kernel_launch(void* const* d_in, const int* in_sizes, int n_in,
                              void* d_out, int out_size, void* d_ws, size_t ws_size,
                              hipStream_t stream) {
  const float* Q = (const float*)d_in[0];
  const float* D = (const float*)d_in[1];
  const int* qmask = (const int*)d_in[2];
  const int* dmask = (const int*)d_in[3];
  float* out = (float*)d_out;
  unsigned short* Qb = (unsigned short*)d_ws;  // 32*32*128 bf16 = 256 KB

  prep_q_kernel<<<(NQ * NM * NH / 4) / 256, 256, 0, stream>>>(Q, qmask, Qb);
  maxsim_kernel<<<ND, 256, 0, stream>>>(D, dmask, Qb, out);
}

// Round 6
// 49.979 us; speedup vs baseline: 2.9531x; 1.7737x over previous
//
#include <hip/hip_runtime.h>
#include <hip/hip_bf16.h>

typedef __attribute__((ext_vector_type(8))) short short8;
typedef __attribute__((ext_vector_type(4))) float f32x4;

#define NQ 32      // queries
#define NM 32      // query tokens
#define NH 128     // head dim
#define ND 512     // docs
#define NN 180     // doc tokens
#define NNP 192    // padded doc tokens (12 tiles of 16)
#define LSTR 136   // LDS row stride in shorts (272 B)

static __device__ __forceinline__ unsigned short f2bf(float x) {
  __hip_bfloat16 h = __float2bfloat16(x);
  return __builtin_bit_cast(unsigned short, h);
}

// Qb = bf16(Q * q_mask), [32*32][128]
__global__ __launch_bounds__(256, 1) void prep_q_kernel(
    const float* __restrict__ Q, const int* __restrict__ qmask,
    unsigned short* __restrict__ Qb) {
  int idx = blockIdx.x * 256 + threadIdx.x;   // float4 index, 32768 total
  int row = idx >> 5;                          // qm row (32 float4 per row)
  float m = (float)qmask[row];
  float4 v = reinterpret_cast<const float4*>(Q)[idx];
  unsigned int lo = (unsigned)f2bf(v.x * m) | ((unsigned)f2bf(v.y * m) << 16);
  unsigned int hi = (unsigned)f2bf(v.z * m) | ((unsigned)f2bf(v.w * m) << 16);
  reinterpret_cast<uint2*>(Qb)[idx] = make_uint2(lo, hi);
}

static __device__ __forceinline__ f32x4 max4(f32x4 a, f32x4 b) {
  f32x4 r;
  r[0] = fmaxf(a[0], b[0]); r[1] = fmaxf(a[1], b[1]);
  r[2] = fmaxf(a[2], b[2]); r[3] = fmaxf(a[3], b[3]);
  return r;
}

// one workgroup per doc d; 4 waves; wave w owns queries w*8..w*8+7, processed in
// pairs. Pair loop is a RUNTIME loop (#pragma unroll 1) so only one pair's
// working set (~175 VGPR) is live. NO VGPR cap: occupancy is grid-limited
// (512 blocks = 2/CU co-resident needs only VGPR<=256, LDS 2x51KB<160KB), so
// capping (R5's (256,2) -> 128 VGPR) only caused scratch spill (165MB FETCH).
// Operands swapped: C[n,m] = mfma(Dfrag, Qfrag); max-over-n = j-fold + xor16/32.
__global__ __launch_bounds__(256) void maxsim_kernel(
    const float* __restrict__ D, const int* __restrict__ dmask,
    const unsigned short* __restrict__ Qb, float* __restrict__ out) {
  __shared__ unsigned short Dlds[NNP * LSTR];  // 52224 B
  const int d = blockIdx.x;
  const int tid = threadIdx.x;
  const int lane = tid & 63;
  const int w = tid >> 6;
  const float NEG = -__builtin_inff();

  // ---- stage masked D -> LDS bf16 ----
  const float4* Dsrc = reinterpret_cast<const float4*>(D) + d * (NN * NH / 4);
  for (int i = tid; i < NN * (NH / 4); i += 256) {
    int row = i >> 5;
    int c4 = i & 31;
    float m = (float)dmask[d * NN + row];
    float4 v = Dsrc[i];
    unsigned int lo = (unsigned)f2bf(v.x * m) | ((unsigned)f2bf(v.y * m) << 16);
    unsigned int hi = (unsigned)f2bf(v.z * m) | ((unsigned)f2bf(v.w * m) << 16);
    *reinterpret_cast<uint2*>(&Dlds[row * LSTR + c4 * 4]) = make_uint2(lo, hi);
  }
  for (int i = tid; i < (NNP - NN) * (NH / 4); i += 256) {  // zero pad rows 180..191
    int row = NN + (i >> 5);
    int c4 = i & 31;
    *reinterpret_cast<uint2*>(&Dlds[row * LSTR + c4 * 4]) = make_uint2(0u, 0u);
  }
  __syncthreads();

  const int bl = lane & 15;   // fragment row(n)/col(m) within tile
  const int bg = lane >> 4;   // k-group / n-quarter

  #pragma unroll 1
  for (int p = 0; p < 4; ++p) {
    const int q0 = w * 8 + p * 2;
    const unsigned short* Qp0 = Qb + (q0 + 0) * (NM * NH);
    const unsigned short* Qp1 = Qb + (q0 + 1) * (NM * NH);

    // B operand fragments for the two queries of this pair (64 VGPR)
    short8 Qf[2][2][4];  // [qi][mt][ks]
    #pragma unroll
    for (int mt = 0; mt < 2; ++mt) {
      #pragma unroll
      for (int ks = 0; ks < 4; ++ks) {
        Qf[0][mt][ks] = *reinterpret_cast<const short8*>(
            Qp0 + (mt * 16 + bl) * NH + ks * 32 + bg * 8);
        Qf[1][mt][ks] = *reinterpret_cast<const short8*>(
            Qp1 + (mt * 16 + bl) * NH + ks * 32 + bg * 8);
      }
    }

    f32x4 run[2][2];  // [qi][mt]
    #pragma unroll
    for (int qi = 0; qi < 2; ++qi)
      #pragma unroll
      for (int mt = 0; mt < 2; ++mt)
        run[qi][mt] = (f32x4){NEG, NEG, NEG, NEG};

    #pragma unroll
    for (int ntp = 0; ntp < 6; ++ntp) {   // 2 n-tiles per iter, Da shared by the pair
      short8 Da[2][4];
      #pragma unroll
      for (int nti = 0; nti < 2; ++nti)
        #pragma unroll
        for (int ks = 0; ks < 4; ++ks)
          Da[nti][ks] = *reinterpret_cast<const short8*>(
              &Dlds[((ntp * 2 + nti) * 16 + bl) * LSTR + ks * 32 + bg * 8]);

      // 8 independent accumulator chains
      f32x4 acc[2][2][2];  // [nti][qi][mt]
      #pragma unroll
      for (int nti = 0; nti < 2; ++nti)
        #pragma unroll
        for (int qi = 0; qi < 2; ++qi)
          #pragma unroll
          for (int mt = 0; mt < 2; ++mt)
            acc[nti][qi][mt] = (f32x4){0.f, 0.f, 0.f, 0.f};

      #pragma unroll
      for (int ks = 0; ks < 4; ++ks)
        #pragma unroll
        for (int nti = 0; nti < 2; ++nti)
          #pragma unroll
          for (int qi = 0; qi < 2; ++qi)
            #pragma unroll
            for (int mt = 0; mt < 2; ++mt)
              acc[nti][qi][mt] = __builtin_amdgcn_mfma_f32_16x16x32_bf16(
                  Da[nti][ks], Qf[qi][mt][ks], acc[nti][qi][mt], 0, 0, 0);

      // fold into running max; tile 11 (ntp==5, nti==1): rows n=176+bg*4+j, only bg==0 real
      #pragma unroll
      for (int nti = 0; nti < 2; ++nti) {
        const bool isTail = (ntp == 5) && (nti == 1);
        #pragma unroll
        for (int qi = 0; qi < 2; ++qi)
          #pragma unroll
          for (int mt = 0; mt < 2; ++mt) {
            f32x4 v = acc[nti][qi][mt];
            if (isTail) {
              #pragma unroll
              for (int j = 0; j < 4; ++j) v[j] = (bg == 0) ? v[j] : NEG;
            }
            run[qi][mt] = max4(run[qi][mt], v);
          }
      }
    }

    // ---- in-loop reduction tail (~10 shuffles per q) ----
    #pragma unroll
    for (int qi = 0; qi < 2; ++qi) {
      float a = fmaxf(fmaxf(run[qi][0][0], run[qi][0][1]),
                      fmaxf(run[qi][0][2], run[qi][0][3]));   // mt=0 (m = bl)
      float b = fmaxf(fmaxf(run[qi][1][0], run[qi][1][1]),
                      fmaxf(run[qi][1][2], run[qi][1][3]));   // mt=1 (m = bl+16)
      a = fmaxf(a, __shfl_xor(a, 16));
      a = fmaxf(a, __shfl_xor(a, 32));
      b = fmaxf(b, __shfl_xor(b, 16));
      b = fmaxf(b, __shfl_xor(b, 32));
      float s = a + b;                  // m = bl and m = bl+16
      s += __shfl_xor(s, 1);            // sum over the 16 bl classes
      s += __shfl_xor(s, 2);
      s += __shfl_xor(s, 4);
      s += __shfl_xor(s, 8);
      if (lane == 0) out[(q0 + qi) * ND + d] = s;
    }
  }
}

extern "C" void kernel_launch(void* const* d_in, const int* in_sizes, int n_in,
                              void* d_out, int out_size, void* d_ws, size_t ws_size,
                              hipStream_t stream) {
  const float* Q = (const float*)d_in[0];
  const float* D = (const float*)d_in[1];
  const int* qmask = (const int*)d_in[2];
  const int* dmask = (const int*)d_in[3];
  float* out = (float*)d_out;
  unsigned short* Qb = (unsigned short*)d_ws;  // 32*32*128 bf16 = 256 KB

  prep_q_kernel<<<(NQ * NM * NH / 4) / 256, 256, 0, stream>>>(Q, qmask, Qb);
  maxsim_kernel<<<ND, 256, 0, stream>>>(D, dmask, Qb, out);
}